// Round 5
// baseline (512.672 us; speedup 1.0000x reference)
//
#include <hip/hip_runtime.h>
#include <hip/hip_bf16.h>
#include <hip/hip_fp16.h>

#define MPTS 200000
#define NCAM 6
#define CIMG 96
#define HF 32
#define WF 88
#define PDIM 128
#define FDIM 224
#define FDIM_P 232            // LDS row pad: dword stride 116 ≡ 20 (mod 32) → conflict-free
#define ORIH 256
#define ORIW 704
#define GZD 32
#define GYD 512
#define GXD 448
#define NCELLS (GZD*GYD*GXD)  // 7,340,032
#define NWORDS (NCELLS/32)    // 229,376 bitmap words
#define PAIR_CAP 16384
#define BN_EPS 1e-5f

// ---- workspace layout (bytes), all offsets 16B-aligned ----
#define OFF_GRID   0UL            // int[NCELLS]            29,360,128 B (NOT memset - bitmap gates reads)
#define OFF_BMAP   29360128UL     // u32[NWORDS]+pad           917,520 B (memset 0)
#define OFF_IMGT   30277648UL     // float[6*32*88*96]       6,488,064 B
#define OFF_DESCM  36765712UL     // uint[M*6]               4,800,000 B
#define OFF_WPACK  OFF_DESCM      // bf16 wpack overlays descm AFTER k_fuse
#define OFF_DESCW  41565712UL     // uint2[M*6]              9,600,000 B
#define OFF_FUSE   51165712UL     // bf16[M*224]            89,600,000 B
#define OFF_CNT    140765712UL    // int[32]
#define OFF_PAIRS  140765840UL    // int2[27*PAIR_CAP]       3,538,944 B
// total ~144.3 MB

#define BPTS (MPTS*32/256)        // 25000 blocks: pts copy (M*32 float4 threads)
#define BIMG (MPTS*24/256)        // 18750 blocks: img sample (M*24 threads)

typedef __attribute__((ext_vector_type(8))) short bf16x8;
typedef __attribute__((ext_vector_type(4))) float f32x4;

__device__ __forceinline__ unsigned short f32_to_bf16bits(float f) {
    __hip_bfloat16 h = __float2bfloat16(f);   // RNE
    return *reinterpret_cast<unsigned short*>(&h);
}

// -------- scatter: grid[cell] = max point index (last-write-wins) + occupancy bit
__global__ __launch_bounds__(256) void k_scatter(const int* __restrict__ vc,
                                                 int* __restrict__ grid,
                                                 unsigned int* __restrict__ bmap) {
    int i = blockIdx.x * 256 + threadIdx.x;
    if (i >= MPTS) return;
    int cz = vc[i*4+1], cy = vc[i*4+2], cx = vc[i*4+3];
    int cell = (cz*GYD + cy)*GXD + cx;
    atomicMax(&grid[cell], i);                 // poison 0xAAAAAAAA is negative -> max=i
    atomicOr(&bmap[cell >> 5], 1u << (cell & 31));
}

// ---------------- transpose img (cam,C,H,W) -> (cam,H,W,C) --------------------
__global__ __launch_bounds__(256) void k_transpose(const float* __restrict__ img,
                                                   float* __restrict__ imgt) {
    int tid = blockIdx.x * 256 + threadIdx.x;
    if (tid >= NCAM*CIMG*HF*WF) return;
    int c = tid % CIMG;
    int r = tid / CIMG;
    int x = r % WF;
    int r2 = r / WF;
    int y = r2 % HF;
    int cam = r2 / HF;
    imgt[tid] = img[((cam*CIMG + c)*HF + y)*WF + x];
}

// ------- projection + full bilinear setup -> per-(point,cam) descriptor ------
// meta: bit15 = active, low bits = clamped base pixel (yb*WF+xb); inactive -> 0
// wts:  4 corner weights (validity folded in) as f16x4; inactive -> zeros
__global__ __launch_bounds__(256) void k_proj(const int* __restrict__ vc,
                                              const float* __restrict__ l2i,
                                              const float* __restrict__ iaug,
                                              const float* __restrict__ laug,
                                              unsigned int* __restrict__ meta,
                                              uint2* __restrict__ wts) {
    int i = blockIdx.x * 256 + threadIdx.x;
    if (i >= MPTS) return;
    float cxf = (float)vc[i*4+3], cyf = (float)vc[i*4+2], czf = (float)vc[i*4+1];
    float a00=laug[0],a01=laug[1],a02=laug[2];
    float a10=laug[4],a11=laug[5],a12=laug[6];
    float a20=laug[8],a21=laug[9],a22=laug[10];
    float t0=laug[3], t1=laug[7], t2=laug[11];
    float det = a00*(a11*a22-a12*a21) - a01*(a10*a22-a12*a20) + a02*(a10*a21-a11*a20);
    float id = 1.0f/det;
    float b00 =  (a11*a22-a12*a21)*id, b01 = -(a01*a22-a02*a21)*id, b02 =  (a01*a12-a02*a11)*id;
    float b10 = -(a10*a22-a12*a20)*id, b11 =  (a00*a22-a02*a20)*id, b12 = -(a00*a12-a02*a10)*id;
    float b20 =  (a10*a21-a11*a20)*id, b21 = -(a00*a21-a01*a20)*id, b22 =  (a00*a11-a01*a10)*id;
    float px = cxf-t0, py = cyf-t1, pz = czf-t2;
    float X = b00*px + b01*py + b02*pz;
    float Y = b10*px + b11*py + b12*pz;
    float Z = b20*px + b21*py + b22*pz;
    #pragma unroll
    for (int cam = 0; cam < NCAM; cam++) {
        const float* Lm = l2i + cam*16;
        float c0 = Lm[0]*X + Lm[1]*Y + Lm[2]*Z  + Lm[3];
        float c1 = Lm[4]*X + Lm[5]*Y + Lm[6]*Z  + Lm[7];
        float c2 = Lm[8]*X + Lm[9]*Y + Lm[10]*Z + Lm[11];
        float z  = fminf(fmaxf(c2, 1e-5f), 100000.0f);
        float vx = c0/z, vy = c1/z, vz = z;
        const float* Am = iaug + cam*16;
        float d0 = Am[0]*vx + Am[1]*vy + Am[2]*vz + Am[3];
        float d1 = Am[4]*vx + Am[5]*vy + Am[6]*vz + Am[7];
        float x = d0 * ((float)(WF-1)/(float)ORIW);
        float y = d1 * ((float)(HF-1)/(float)ORIH);
        bool act = (x > -1.0f) && (x < (float)WF) && (y > -1.0f) && (y < (float)HF);
        float x0f = floorf(x), y0f = floorf(y);
        int x0 = (int)x0f, y0 = (int)y0f;
        float wx1 = x - x0f, wy1 = y - y0f;
        float wx0 = 1.f - wx1, wy0 = 1.f - wy1;
        float ux0, ux1, uy0, uy1;
        if (x0 < 0)            { ux0 = wx1; ux1 = 0.f; }
        else if (x0 >= WF-1)   { ux0 = 0.f; ux1 = wx0; }
        else                   { ux0 = wx0; ux1 = wx1; }
        if (y0 < 0)            { uy0 = wy1; uy1 = 0.f; }
        else if (y0 >= HF-1)   { uy0 = 0.f; uy1 = wy0; }
        else                   { uy0 = wy0; uy1 = wy1; }
        int xb = min(max(x0, 0), WF-2);
        int yb = min(max(y0, 0), HF-2);
        unsigned int m = 0u;
        __half2 h01 = __floats2half2_rn(0.f, 0.f), h23 = h01;
        if (act) {
            m = 0x8000u | (unsigned int)(yb*WF + xb);
            h01 = __floats2half2_rn(ux0*uy0, ux1*uy0);
            h23 = __floats2half2_rn(ux0*uy1, ux1*uy1);
        }
        meta[i*6 + cam] = m;
        uint2 wv;
        wv.x = *reinterpret_cast<unsigned int*>(&h01);
        wv.y = *reinterpret_cast<unsigned int*>(&h23);
        wts[i*6 + cam] = wv;
    }
}

// ------- fuse: blocks [0,BPTS) stream pts->bf16; blocks [BPTS,..) sample img --
// img part: gathers are UNCONDITIONAL (inactive cam -> pixel 0, weight 0):
// zero divergence, 24 independent 16B gathers in flight per thread.
__global__ __launch_bounds__(256) void k_fuse(const float4* __restrict__ pts4,
                                              const float4* __restrict__ imgt4,
                                              const unsigned int* __restrict__ meta,
                                              const uint2* __restrict__ wts,
                                              ushort4* __restrict__ fuse4) {
    int b = blockIdx.x;
    if (b < BPTS) {
        int t = b*256 + threadIdx.x;
        int i = t >> 5, c4 = t & 31;
        float4 v = pts4[t];
        ushort4 o;
        o.x = f32_to_bf16bits(v.x); o.y = f32_to_bf16bits(v.y);
        o.z = f32_to_bf16bits(v.z); o.w = f32_to_bf16bits(v.w);
        fuse4[i*56 + c4] = o;
    } else {
        int t = (b - BPTS)*256 + threadIdx.x;    // over M*24
        int i = t / 24, sg = t % 24;
        float4 acc = make_float4(0.f, 0.f, 0.f, 0.f);
        #pragma unroll
        for (int cam = 0; cam < NCAM; cam++) {
            unsigned int m = meta[i*6 + cam];
            uint2 w = wts[i*6 + cam];
            int pix = (int)(m & 0x7FFFu);        // 0 when inactive
            const float4* base = imgt4 + (size_t)cam*(HF*WF*(CIMG/4)) + (size_t)pix*(CIMG/4) + sg;
            float4 t00 = base[0];
            float4 t01 = base[CIMG/4];
            float4 t10 = base[WF*(CIMG/4)];
            float4 t11 = base[(WF+1)*(CIMG/4)];
            float2 w01 = __half22float2(*reinterpret_cast<const __half2*>(&w.x));
            float2 w23 = __half22float2(*reinterpret_cast<const __half2*>(&w.y));
            acc.x += t00.x*w01.x + t01.x*w01.y + t10.x*w23.x + t11.x*w23.y;
            acc.y += t00.y*w01.x + t01.y*w01.y + t10.y*w23.x + t11.y*w23.y;
            acc.z += t00.z*w01.x + t01.z*w01.y + t10.z*w23.x + t11.z*w23.y;
            acc.w += t00.w*w01.x + t01.w*w01.y + t10.w*w23.x + t11.w*w23.y;
        }
        ushort4 o;
        o.x = f32_to_bf16bits(acc.x); o.y = f32_to_bf16bits(acc.y);
        o.z = f32_to_bf16bits(acc.z); o.w = f32_to_bf16bits(acc.w);
        fuse4[i*56 + 32 + sg] = o;
    }
}

// ---------------- pack conv_w into bf16 MFMA B-fragment layout ----------------
__global__ __launch_bounds__(256) void k_wpack(const float* __restrict__ conv,
                                               ushort4* __restrict__ wp) {
    int tid = blockIdx.x * 256 + threadIdx.x;
    if (tid >= 27*7*8*64) return;
    int lane = tid & 63;
    int nt   = (tid >> 6) & 7;
    int kk   = (tid >> 9) % 7;
    int k27  = tid / 3584;
    int n     = nt*16 + (lane & 15);
    int kbase = kk*32 + (lane >> 4)*8;
    const float* src = conv + ((size_t)k27*FDIM + kbase)*PDIM + n;
    ushort4 lo, hi;
    lo.x = f32_to_bf16bits(src[0*PDIM]);
    lo.y = f32_to_bf16bits(src[1*PDIM]);
    lo.z = f32_to_bf16bits(src[2*PDIM]);
    lo.w = f32_to_bf16bits(src[3*PDIM]);
    hi.x = f32_to_bf16bits(src[4*PDIM]);
    hi.y = f32_to_bf16bits(src[5*PDIM]);
    hi.z = f32_to_bf16bits(src[6*PDIM]);
    hi.w = f32_to_bf16bits(src[7*PDIM]);
    wp[tid*2]   = lo;
    wp[tid*2+1] = hi;
}

// ------- pair lists: bitmap probe (9 x 2-word loads, L2-hot) then grid gather
//         only on hits (~140k of 5.2M); ballot-aggregated counters ------------
__global__ __launch_bounds__(256) void k_pairs(const int* __restrict__ vc,
                                               const int* __restrict__ grid,
                                               const unsigned int* __restrict__ bmap,
                                               int* __restrict__ cnt,
                                               int2* __restrict__ pairs) {
    int i = blockIdx.x * 256 + threadIdx.x;
    bool act = (i < MPTS);
    int cz = 0, cy = 0, cx = 0;
    if (act) { cz = vc[i*4+1]; cy = vc[i*4+2]; cx = vc[i*4+3]; }

    unsigned int hitmask = 0;
    #pragma unroll
    for (int dzy = 0; dzy < 9; dzy++) {
        int dz = dzy/3 - 1, dy = dzy%3 - 1;
        int nz = cz + dz, ny = cy + dy;
        if (act && nz >= 0 && nz < GZD && ny >= 0 && ny < GYD) {
            int base  = (nz*GYD + ny)*GXD + cx;       // bit index for dx=0
            int start = max(base - 1, 0);
            int w     = start >> 5;
            unsigned long long pr = ((unsigned long long)bmap[w+1] << 32) | bmap[w];
            unsigned long long sh = pr >> (start & 31);
            if (cx-1 >= 0  && ((sh >> (base-1-start)) & 1)) hitmask |= 1u << (dzy*3 + 0);
            if (              ((sh >> (base  -start)) & 1)) hitmask |= 1u << (dzy*3 + 1);
            if (cx+1 < GXD && ((sh >> (base+1-start)) & 1)) hitmask |= 1u << (dzy*3 + 2);
        }
    }
    hitmask &= ~(1u << 13);                           // drop center

    __shared__ int s_wcnt[4][27];
    __shared__ int s_wbase[4][27];
    int wv = threadIdx.x >> 6, ln = threadIdx.x & 63;
    int nid[27];
    int rnk[27];
    #pragma unroll
    for (int k = 0; k < 27; k++) {
        if (k == 13) continue;
        int id = -1;
        if ((hitmask >> k) & 1) {
            int dz = k/9 - 1, dy = (k/3)%3 - 1, dx = k%3 - 1;
            id = grid[((cz+dz)*GYD + (cy+dy))*GXD + (cx+dx)];
        }
        nid[k] = id;
        unsigned long long mm = __ballot(id >= 0);
        if (ln == 0) s_wcnt[wv][k] = __popcll(mm);
        rnk[k] = __popcll(mm & ((1ull << ln) - 1ull));
    }
    __syncthreads();
    if (threadIdx.x < 27 && threadIdx.x != 13) {
        int k = threadIdx.x;
        int c0 = s_wcnt[0][k], c1 = s_wcnt[1][k], c2 = s_wcnt[2][k], c3 = s_wcnt[3][k];
        int tot = c0 + c1 + c2 + c3;
        int bse = (tot > 0) ? atomicAdd(&cnt[k], tot) : 0;
        s_wbase[0][k] = bse;
        s_wbase[1][k] = bse + c0;
        s_wbase[2][k] = bse + c0 + c1;
        s_wbase[3][k] = bse + c0 + c1 + c2;
    }
    __syncthreads();
    #pragma unroll
    for (int k = 0; k < 27; k++) {
        if (k == 13) continue;
        if (nid[k] >= 0) {
            int slot = s_wbase[wv][k] + rnk[k];
            if (slot < PAIR_CAP) pairs[k*PAIR_CAP + slot] = make_int2(i, nid[k]);
        }
    }
}

// ---- MFMA micro-kernel pieces ------------------------------------------------
__device__ __forceinline__ void fill_tile_bf16(unsigned short (*s_fb)[FDIM_P],
                                               const int* s_j,
                                               const uint4* __restrict__ fuse16,
                                               int tid) {
    for (int idx = tid; idx < 32*28; idx += 256) {
        int r = idx / 28, c = idx % 28;
        int j = s_j[r];
        uint4 v = make_uint4(0u, 0u, 0u, 0u);
        if (j >= 0) v = fuse16[(size_t)j*28 + c];
        *reinterpret_cast<uint4*>(&s_fb[r][c*8]) = v;
    }
}

__device__ __forceinline__ void gemm_mfma(const unsigned short (*s_fb)[FDIM_P],
                                          const bf16x8* __restrict__ wpb,
                                          int k27, int lane, int wv,
                                          f32x4 acc[2][2]) {
    int quad = lane >> 4, l15 = lane & 15;
    #pragma unroll
    for (int kk = 0; kk < 7; kk++) {
        bf16x8 a0 = *reinterpret_cast<const bf16x8*>(&s_fb[l15     ][kk*32 + quad*8]);
        bf16x8 a1 = *reinterpret_cast<const bf16x8*>(&s_fb[16 + l15][kk*32 + quad*8]);
        bf16x8 b0 = wpb[(((k27*7 + kk)*8) + wv*2 + 0)*64 + lane];
        bf16x8 b1 = wpb[(((k27*7 + kk)*8) + wv*2 + 1)*64 + lane];
        acc[0][0] = __builtin_amdgcn_mfma_f32_16x16x32_bf16(a0, b0, acc[0][0], 0, 0, 0);
        acc[1][0] = __builtin_amdgcn_mfma_f32_16x16x32_bf16(a1, b0, acc[1][0], 0, 0, 0);
        acc[0][1] = __builtin_amdgcn_mfma_f32_16x16x32_bf16(a0, b1, acc[0][1], 0, 0, 0);
        acc[1][1] = __builtin_amdgcn_mfma_f32_16x16x32_bf16(a1, b1, acc[1][1], 0, 0, 0);
    }
}

// ---------------- neighbor GEMMs: per (k, 32-pair tile), atomic scatter-add ----
__global__ __launch_bounds__(256) void k_nbr(const int2* __restrict__ pairs,
                                             const int* __restrict__ cnt,
                                             const uint4* __restrict__ fuse16,
                                             const bf16x8* __restrict__ wpb,
                                             float* __restrict__ out) {
    int k = blockIdx.y;
    if (k >= 13) k += 1;
    int n = cnt[k];
    if (n > PAIR_CAP) n = PAIR_CAP;
    int p0 = blockIdx.x * 32;
    if (p0 >= n) return;
    int nn = min(32, n - p0);

    __shared__ int s_i[32];
    __shared__ int s_j[32];
    __shared__ unsigned short s_fb[32][FDIM_P];
    int tid = threadIdx.x;
    if (tid < 32) {
        if (tid < nn) { int2 pr = pairs[k*PAIR_CAP + p0 + tid]; s_i[tid] = pr.x; s_j[tid] = pr.y; }
        else          { s_i[tid] = -1; s_j[tid] = -1; }
    }
    __syncthreads();
    fill_tile_bf16(s_fb, s_j, fuse16, tid);
    __syncthreads();

    int lane = tid & 63, wv = tid >> 6;
    int quad = lane >> 4, l15 = lane & 15;
    f32x4 acc[2][2] = {};
    gemm_mfma(s_fb, wpb, k, lane, wv, acc);

    #pragma unroll
    for (int nt = 0; nt < 2; nt++) {
        int col = wv*32 + nt*16 + l15;
        #pragma unroll
        for (int mt = 0; mt < 2; mt++) {
            #pragma unroll
            for (int r = 0; r < 4; r++) {
                int row = mt*16 + quad*4 + r;
                int ii = s_i[row];
                if (ii >= 0) unsafeAtomicAdd(&out[(size_t)ii*PDIM + col], acc[mt][nt][r]);
            }
        }
    }
}

// ---------------- center GEMM (k=13, all points) + BN + ReLU epilogue ---------
__global__ __launch_bounds__(256) void k_center(const int* __restrict__ vc,
                                                const int* __restrict__ grid,
                                                const uint4* __restrict__ fuse16,
                                                const bf16x8* __restrict__ wpb,
                                                const float* __restrict__ gamma,
                                                const float* __restrict__ beta,
                                                const float* __restrict__ mean,
                                                const float* __restrict__ var,
                                                float* __restrict__ out) {
    int i0 = blockIdx.x * 32;
    __shared__ int s_j[32];
    __shared__ unsigned short s_fb[32][FDIM_P];
    int tid = threadIdx.x;
    if (tid < 32) {
        int i = i0 + tid;
        int cz = vc[i*4+1], cy = vc[i*4+2], cx = vc[i*4+3];
        s_j[tid] = grid[(cz*GYD + cy)*GXD + cx];   // own cell: always valid
    }
    __syncthreads();
    fill_tile_bf16(s_fb, s_j, fuse16, tid);
    __syncthreads();

    int lane = tid & 63, wv = tid >> 6;
    int quad = lane >> 4, l15 = lane & 15;
    f32x4 acc[2][2] = {};
    gemm_mfma(s_fb, wpb, 13, lane, wv, acc);

    #pragma unroll
    for (int nt = 0; nt < 2; nt++) {
        int col = wv*32 + nt*16 + l15;
        float g  = gamma[col], bb = beta[col], mn = mean[col];
        float rs = rsqrtf(var[col] + BN_EPS);
        #pragma unroll
        for (int mt = 0; mt < 2; mt++) {
            #pragma unroll
            for (int r = 0; r < 4; r++) {
                int row = mt*16 + quad*4 + r;
                size_t o = (size_t)(i0 + row)*PDIM + col;
                float v = out[o] + acc[mt][nt][r];
                v = (v - mn)*rs*g + bb;
                out[o] = fmaxf(v, 0.f);
            }
        }
    }
}

extern "C" void kernel_launch(void* const* d_in, const int* in_sizes, int n_in,
                              void* d_out, int out_size, void* d_ws, size_t ws_size,
                              hipStream_t stream) {
    const float* pts   = (const float*)d_in[0];
    const int*   vc    = (const int*)d_in[1];
    const float* img   = (const float*)d_in[2];
    const float* l2i   = (const float*)d_in[3];
    const float* iaug  = (const float*)d_in[4];
    const float* laug  = (const float*)d_in[5];
    const float* conv  = (const float*)d_in[6];
    const float* gamma = (const float*)d_in[7];
    const float* beta  = (const float*)d_in[8];
    const float* mean  = (const float*)d_in[9];
    const float* var   = (const float*)d_in[10];
    float* out = (float*)d_out;

    char* ws = (char*)d_ws;
    int*          grid  = (int*)(ws + OFF_GRID);
    unsigned int* bmap  = (unsigned int*)(ws + OFF_BMAP);
    float*        imgt  = (float*)(ws + OFF_IMGT);
    unsigned int* descm = (unsigned int*)(ws + OFF_DESCM);
    uint2*        descw = (uint2*)(ws + OFF_DESCW);
    ushort4*      wp    = (ushort4*)(ws + OFF_WPACK);
    ushort4*      fuse4 = (ushort4*)(ws + OFF_FUSE);
    int*          cnt   = (int*)(ws + OFF_CNT);
    int2*         pairs = (int2*)(ws + OFF_PAIRS);
    const uint4*  fuse16 = (const uint4*)fuse4;
    const bf16x8* wpb    = (const bf16x8*)wp;

    hipMemsetAsync(bmap, 0, (size_t)NWORDS*4 + 16, stream);        // bitmap = 0 (grid NOT memset)
    hipMemsetAsync(cnt, 0, 32*4, stream);
    hipMemsetAsync(d_out, 0, (size_t)out_size*4, stream);

    int blocksM = (MPTS + 255)/256;
    k_scatter<<<blocksM, 256, 0, stream>>>(vc, grid, bmap);
    k_transpose<<<(NCAM*CIMG*HF*WF + 255)/256, 256, 0, stream>>>(img, imgt);
    k_proj<<<blocksM, 256, 0, stream>>>(vc, l2i, iaug, laug, descm, descw);
    k_fuse<<<BPTS + BIMG, 256, 0, stream>>>((const float4*)pts, (const float4*)imgt,
                                            descm, descw, fuse4);
    k_wpack<<<(27*7*8*64 + 255)/256, 256, 0, stream>>>(conv, wp);   // after k_fuse (descm overlay)
    k_pairs<<<blocksM, 256, 0, stream>>>(vc, grid, bmap, cnt, pairs);
    k_nbr<<<dim3(PAIR_CAP/32, 26), 256, 0, stream>>>(pairs, cnt, fuse16, wpb, out);
    k_center<<<(MPTS + 31)/32, 256, 0, stream>>>(vc, grid, fuse16, wpb,
                                                 gamma, beta, mean, var, out);
}